// Round 5
// baseline (139.839 us; speedup 1.0000x reference)
//
#include <hip/hip_runtime.h>

// Problem constants
#define Bq 32
#define Sq 2048
#define Dq 128
#define Tq 8
#define Mq (Bq * Sq)   // 65536 rows

typedef __attribute__((ext_vector_type(8))) short bf16x8;
typedef __attribute__((ext_vector_type(4))) float f32x4;   // true vector type (nontemporal-compatible)

static __device__ __forceinline__ unsigned short f2bf(float f) {
    unsigned int u = __float_as_uint(f);
    unsigned int r = (u + 0x7FFFu + ((u >> 16) & 1u)) >> 16;
    return (unsigned short)r;
}

// ---------------------------------------------------------------------------
// Kernel 1: W' = (W + I) [T,D,D] fp32 -> bf16, swizzled into MFMA B-fragment
// order (softmax weights sum to 1 -> residual folds into the diagonal).
// B operand of mfma_f32_16x16x32_bf16: lane holds B[k = quad*8 + j][n = lane&15]
// = W'[e = n][d = k].  Flat index (((t*8 + nt)*4 + k)*64 + lane)*8 + j ->
// hot-loop loads are lane-contiguous 16B = perfectly coalesced.
// ---------------------------------------------------------------------------
__global__ void prep_kernel(const float* __restrict__ W, unsigned short* __restrict__ wsw) {
    int i = blockIdx.x * 256 + threadIdx.x;   // grid covers exactly T*D*D = 131072
    int j    = i & 7;
    int lane = (i >> 3) & 63;
    int k    = (i >> 9) & 3;
    int n    = (i >> 11) & 7;
    int t    = i >> 14;
    int e = n * 16 + (lane & 15);
    int d = k * 32 + (lane >> 4) * 8 + j;
    float w = W[(t * 128 + e) * 128 + d];
    if (e == d) w += 1.0f;                    // identity fold (residual)
    wsw[i] = f2bf(w);
}

// ---------------------------------------------------------------------------
// Kernel 2: 64-row x 128-col tile per 256-thr block, grid 1024 (4 blocks/CU
// worth of work, 3 resident at launch_bounds(256,3) -> 12 waves/CU).
// Wave tile 32r x 64c (2 mt x 4 nt): per-wave register state
// a[2][4]+o[2][4]+y[2][4]+bf[2][4]+s[2] ~ 160 VGPR -> fits 3 waves/EU, NO spill
// (R4's 44us was spill/remat: 190 VGPR live vs 120 allocated, 2 waves/EU).
// K-streamed W with 1-k-iter prefetch; bias folded into MFMA C-init.
// ---------------------------------------------------------------------------
__global__ __launch_bounds__(256, 3) void main_kernel(const float* __restrict__ x,
                                                      const unsigned short* __restrict__ wsw,
                                                      const float* __restrict__ bx,
                                                      const float* __restrict__ p,
                                                      float* __restrict__ out) {
    __shared__ unsigned short xs[64][136];   // 17.4 KB; +16B pad keeps b128 alignment
    __shared__ float simT[Tq][64];
    __shared__ float bxl[Tq][128];
    __shared__ f32x4 p4[Tq][32];
    __shared__ float pinv[Tq];

    int tid = threadIdx.x;
    size_t m0 = (size_t)blockIdx.x * 64;

    int r = tid >> 2;      // local row 0..63
    int h = tid & 3;       // quarter-row 0..3 (32 floats each)

    // issue x loads early (nontemporal: read exactly once, keep L2 for W)
    const f32x4* xg = reinterpret_cast<const f32x4*>(x + (m0 + r) * 128) + h * 8;
    f32x4 xv[8];
    #pragma unroll
    for (int j = 0; j < 8; j++) xv[j] = __builtin_nontemporal_load(xg + j);

    // stage p (8x128) and bias (8x128); pinv from global in parallel
    reinterpret_cast<f32x4*>(&p4[0][0])[tid] = reinterpret_cast<const f32x4*>(p)[tid];
    reinterpret_cast<f32x4*>(&bxl[0][0])[tid] = reinterpret_cast<const f32x4*>(bx)[tid];
    if (tid < Tq) {
        const f32x4* pg = reinterpret_cast<const f32x4*>(p) + tid * 32;
        float s = 0.f;
        #pragma unroll
        for (int i = 0; i < 32; i++) {
            f32x4 v = pg[i];
            s += v.x * v.x + v.y * v.y + v.z * v.z + v.w * v.w;
        }
        pinv[tid] = rsqrtf(s);
    }
    __syncthreads();

    // --- fp32 dots + |x|^2 over quarter-row, bf16 convert+store ---
    float dot[Tq];
    #pragma unroll
    for (int t = 0; t < Tq; t++) dot[t] = 0.f;
    float ssq = 0.f;
    #pragma unroll
    for (int j = 0; j < 8; j++) {
        f32x4 v = xv[j];
        ssq += v.x * v.x + v.y * v.y + v.z * v.z + v.w * v.w;
        #pragma unroll
        for (int t = 0; t < Tq; t++) {
            f32x4 pv = p4[t][h * 8 + j];
            dot[t] += v.x * pv.x + v.y * pv.y + v.z * pv.z + v.w * pv.w;
        }
    }
    #pragma unroll
    for (int jj = 0; jj < 4; jj++) {
        f32x4 v0 = xv[2 * jj], v1 = xv[2 * jj + 1];
        bf16x8 b;
        b[0] = (short)f2bf(v0.x); b[1] = (short)f2bf(v0.y);
        b[2] = (short)f2bf(v0.z); b[3] = (short)f2bf(v0.w);
        b[4] = (short)f2bf(v1.x); b[5] = (short)f2bf(v1.y);
        b[6] = (short)f2bf(v1.z); b[7] = (short)f2bf(v1.w);
        *reinterpret_cast<bf16x8*>(&xs[r][h * 32 + jj * 8]) = b;
    }
    // reduce over the 4 lanes of each row (groups of 4 are lane-aligned)
    ssq += __shfl_xor(ssq, 1); ssq += __shfl_xor(ssq, 2);
    #pragma unroll
    for (int t = 0; t < Tq; t++) {
        dot[t] += __shfl_xor(dot[t], 1);
        dot[t] += __shfl_xor(dot[t], 2);
    }
    float xinv = rsqrtf(ssq);
    float c[Tq], mx = -1e30f;
    #pragma unroll
    for (int t = 0; t < Tq; t++) {
        c[t] = dot[t] * xinv * pinv[t];
        mx = fmaxf(mx, c[t]);
    }
    float sum = 0.f;
    #pragma unroll
    for (int t = 0; t < Tq; t++) { c[t] = __expf(c[t] - mx); sum += c[t]; }
    float inv = 1.f / sum;
    simT[2 * h][r]     = c[2 * h] * inv;
    simT[2 * h + 1][r] = c[2 * h + 1] * inv;
    __syncthreads();

    // --- GEMM phase: wave (wid>>1 -> mrow 0/32, wid&1 -> ncol 0/64) ---
    int wid  = tid >> 6;
    int lane = tid & 63;
    int l16  = lane & 15;
    int quad = lane >> 4;
    int mrow = (wid >> 1) * 32;
    int ncol = (wid & 1) * 64;
    int nt0  = (wid & 1) * 4;

    // A fragments: lane holds A[m=lane&15][k=quad*8+j]; reused across all 8 t.
    bf16x8 a[2][4];
    #pragma unroll
    for (int mt = 0; mt < 2; mt++)
        #pragma unroll
        for (int k = 0; k < 4; k++)
            a[mt][k] = *reinterpret_cast<const bf16x8*>(&xs[mrow + mt * 16 + l16][k * 32 + quad * 8]);

    f32x4 o[2][4] = {};   // persistent weighted accumulators (32 VGPR)

    const bf16x8* wbase = reinterpret_cast<const bf16x8*>(wsw);
    bf16x8 bf[2][4];      // k-level double buffer (32 VGPR)
    #pragma unroll
    for (int n = 0; n < 4; n++)
        bf[0][n] = wbase[((size_t)(0 * 8 + nt0 + n) * 4 + 0) * 64 + lane];

    #pragma unroll 1
    for (int t = 0; t < Tq; t++) {
        f32x4 s[2];
        #pragma unroll
        for (int mt = 0; mt < 2; mt++)
            s[mt] = *reinterpret_cast<const f32x4*>(&simT[t][mrow + mt * 16 + quad * 4]);

        // y init = bias (C/D row index rr doesn't change the column -> splat)
        f32x4 y[2][4];
        #pragma unroll
        for (int n = 0; n < 4; n++) {
            float bias = bxl[t][ncol + n * 16 + l16];
            y[0][n] = (f32x4){bias, bias, bias, bias};
            y[1][n] = (f32x4){bias, bias, bias, bias};
        }

        #pragma unroll
        for (int k = 0; k < 4; k++) {
            // prefetch next k (wraps to (t+1, 0); t=7 wraps to t=0, unused)
            {
                int kn = (k + 1) & 3;
                int tn = (k == 3) ? ((t + 1) & 7) : t;
                #pragma unroll
                for (int n = 0; n < 4; n++)
                    bf[(k + 1) & 1][n] = wbase[((size_t)(tn * 8 + nt0 + n) * 4 + kn) * 64 + lane];
            }
            #pragma unroll
            for (int n = 0; n < 4; n++)
                #pragma unroll
                for (int mt = 0; mt < 2; mt++)
                    y[mt][n] = __builtin_amdgcn_mfma_f32_16x16x32_bf16(a[mt][k], bf[k & 1][n], y[mt][n], 0, 0, 0);
        }
        #pragma unroll
        for (int mt = 0; mt < 2; mt++)
            #pragma unroll
            for (int n = 0; n < 4; n++)
                #pragma unroll
                for (int rr = 0; rr < 4; rr++)
                    o[mt][n][rr] += s[mt][rr] * y[mt][n][rr];
    }

    // --- epilogue: pure NT stores. C/D layout: col=lane&15, row=quad*4+reg ---
    #pragma unroll
    for (int mt = 0; mt < 2; mt++)
        #pragma unroll
        for (int rr = 0; rr < 4; rr++) {
            size_t row = m0 + mrow + mt * 16 + quad * 4 + rr;
            #pragma unroll
            for (int n = 0; n < 4; n++) {
                size_t idx = row * 128 + ncol + n * 16 + l16;
                __builtin_nontemporal_store(o[mt][n][rr], out + idx);
            }
        }
}

extern "C" void kernel_launch(void* const* d_in, const int* in_sizes, int n_in,
                              void* d_out, int out_size, void* d_ws, size_t ws_size,
                              hipStream_t stream) {
    const float* x   = (const float*)d_in[0];   // [B,S,D] fp32
    const float* Wx  = (const float*)d_in[1];   // [T,D,D] fp32
    const float* bx  = (const float*)d_in[2];   // [T,D]   fp32
    const float* p   = (const float*)d_in[3];   // [T,1,D] fp32
    float* out = (float*)d_out;

    unsigned short* wsw = (unsigned short*)d_ws;   // 131072 bf16 = 256 KB

    prep_kernel<<<dim3(512), dim3(256), 0, stream>>>(Wx, wsw);
    main_kernel<<<dim3(Mq / 64), dim3(256), 0, stream>>>(x, wsw, bx, p, out);
}

// Round 6
// 124.655 us; speedup vs baseline: 1.1218x; 1.1218x over previous
//
#include <hip/hip_runtime.h>

// Problem constants
#define Tq 8
#define Mq 65536   // B*S rows

typedef short bf16x8 __attribute__((ext_vector_type(8)));
typedef float f32x4 __attribute__((ext_vector_type(4)));

static __device__ __forceinline__ unsigned short f2bf(float f) {
    unsigned int u = __float_as_uint(f);
    unsigned int r = (u + 0x7FFFu + ((u >> 16) & 1u)) >> 16;
    return (unsigned short)r;
}

// ---------------------------------------------------------------------------
// prep: blocks 0..511: W' = (W + I) fp32->bf16 in MFMA B-fragment order
//       (identity fold: softmax weights sum to 1 -> residual in diagonal).
//       block 512: P fragments (p in B-layout, cols 8..15 zero) for MFMA dots.
// Fragment flat index: (((t*8+nt)*4+k)*64+lane)*8+j  -> lane-contiguous 16B.
// ---------------------------------------------------------------------------
__global__ void prep_kernel(const float* __restrict__ W, const float* __restrict__ p,
                            unsigned short* __restrict__ ws) {
    int b = blockIdx.x;
    if (b < 512) {
        int i = b * 256 + threadIdx.x;   // T*D*D = 131072
        int j    = i & 7;
        int lane = (i >> 3) & 63;
        int k    = (i >> 9) & 3;
        int n    = (i >> 11) & 7;
        int t    = i >> 14;
        int e = n * 16 + (lane & 15);
        int d = k * 32 + (lane >> 4) * 8 + j;
        float w = W[(t * 128 + e) * 128 + d];
        if (e == d) w += 1.0f;
        ws[i] = f2bf(w);
    } else {
        // P fragments: 4096 shorts at offset 131072. index (k*64+lane)*8+j
        #pragma unroll
        for (int u = 0; u < 16; u++) {
            int i = u * 256 + threadIdx.x;
            int j    = i & 7;
            int lane = (i >> 3) & 63;
            int k    = i >> 9;
            int l16  = lane & 15;
            int quad = lane >> 4;
            int d = k * 32 + quad * 8 + j;
            float v = (l16 < Tq) ? p[l16 * 128 + d] : 0.0f;
            ws[131072 + i] = f2bf(v);
        }
    }
}

// ---------------------------------------------------------------------------
// main: block = 128 rows x 64 cols, 4 waves stacked by rows (32 rows each),
// ALL waves on the same 64 cols -> W fragments shared via L1 (W_t slice 16KB).
// No x-LDS: each lane loads its own A-fragments straight from global; ssq via
// quad-butterfly. p-dots via MFMA with prepped P fragment; softmax cross-lane
// (t = lane&15, butterfly xor 1/2/4); sim is already in C-layout -> per-t
// weights via one f32x4 shuffle. LDS: only bias slice + pinv (~2.3 KB).
// ---------------------------------------------------------------------------
__global__ __launch_bounds__(256, 3) void main_kernel(const float* __restrict__ x,
                                                      const unsigned short* __restrict__ wsw,
                                                      const float* __restrict__ bx,
                                                      const float* __restrict__ p,
                                                      float* __restrict__ out) {
    __shared__ float bxl[Tq][64];
    __shared__ float pinv[Tq];

    int tid  = threadIdx.x;
    int bid  = blockIdx.x;
    int rb   = bid >> 1;
    int cb   = bid & 1;
    int wid  = tid >> 6;
    int lane = tid & 63;
    int l16  = lane & 15;
    int quad = lane >> 4;
    size_t wrow = (size_t)rb * 128 + wid * 32;   // wave's 32-row base

    // ---- stage bias slice (8 x 64) + pinv ----
    {
        int c  = tid & 63;
        int t2 = tid >> 6;   // 0..3
        bxl[t2][c]     = bx[t2 * 128 + cb * 64 + c];
        bxl[t2 + 4][c] = bx[(t2 + 4) * 128 + cb * 64 + c];
    }
    if (tid < Tq) {
        const f32x4* pg = reinterpret_cast<const f32x4*>(p) + tid * 32;
        float s = 0.f;
        #pragma unroll
        for (int i = 0; i < 32; i++) {
            f32x4 v = pg[i];
            s += v.x * v.x + v.y * v.y + v.z * v.z + v.w * v.w;
        }
        pinv[tid] = rsqrtf(s);
    }

    // ---- A fragments direct from global + per-row |x|^2 ----
    // lane (quad,l16) of m-tile mt: row = wrow + mt*16 + l16,
    // cols k*32 + quad*8 .. +7  (exactly this lane's MFMA A-fragment).
    bf16x8 a[2][4];
    float xinv[2];
    #pragma unroll
    for (int mt = 0; mt < 2; mt++) {
        const f32x4* xr = reinterpret_cast<const f32x4*>(x + (wrow + mt * 16 + l16) * 128);
        float ssq = 0.f;
        #pragma unroll
        for (int k = 0; k < 4; k++) {
            f32x4 v0 = __builtin_nontemporal_load(xr + k * 8 + quad * 2);
            f32x4 v1 = __builtin_nontemporal_load(xr + k * 8 + quad * 2 + 1);
            ssq += v0.x * v0.x + v0.y * v0.y + v0.z * v0.z + v0.w * v0.w
                 + v1.x * v1.x + v1.y * v1.y + v1.z * v1.z + v1.w * v1.w;
            bf16x8 f;
            f[0] = (short)f2bf(v0.x); f[1] = (short)f2bf(v0.y);
            f[2] = (short)f2bf(v0.z); f[3] = (short)f2bf(v0.w);
            f[4] = (short)f2bf(v1.x); f[5] = (short)f2bf(v1.y);
            f[6] = (short)f2bf(v1.z); f[7] = (short)f2bf(v1.w);
            a[mt][k] = f;
        }
        // sum the 4 quads (each holds 32 of the row's 128 squares)
        ssq += __shfl_xor(ssq, 16);
        ssq += __shfl_xor(ssq, 32);
        xinv[mt] = rsqrtf(ssq);
    }

    // ---- p-dots via MFMA (cols = t for l16<8) ----
    const bf16x8* pf = reinterpret_cast<const bf16x8*>(wsw) + 16384;  // 131072 shorts /8
    bf16x8 pfrag[4];
    #pragma unroll
    for (int k = 0; k < 4; k++) pfrag[k] = pf[k * 64 + lane];
    f32x4 d[2] = {};
    #pragma unroll
    for (int k = 0; k < 4; k++) {
        d[0] = __builtin_amdgcn_mfma_f32_16x16x32_bf16(a[0][k], pfrag[k], d[0], 0, 0, 0);
        d[1] = __builtin_amdgcn_mfma_f32_16x16x32_bf16(a[1][k], pfrag[k], d[1], 0, 0, 0);
    }

    __syncthreads();   // pinv + bxl ready

    // ---- cosine + softmax, cross-lane (t = l16; rows = quad*4+rr) ----
    float pv = pinv[l16 & 7];
    f32x4 sim[2];
    #pragma unroll
    for (int mt = 0; mt < 2; mt++) {
        f32x4 c;
        #pragma unroll
        for (int rr = 0; rr < 4; rr++) {
            // xinv holds row (.. + l16); need row (.. + quad*4+rr)
            float xir = __shfl(xinv[mt], (lane & 48) | (quad * 4 + rr));
            c[rr] = d[mt][rr] * xir * pv;
        }
        f32x4 mx = c;
        #pragma unroll
        for (int m = 1; m <= 4; m <<= 1)
            #pragma unroll
            for (int rr = 0; rr < 4; rr++) mx[rr] = fmaxf(mx[rr], __shfl_xor(mx[rr], m));
        f32x4 e;
        #pragma unroll
        for (int rr = 0; rr < 4; rr++) e[rr] = __expf(c[rr] - mx[rr]);
        f32x4 sm = e;
        #pragma unroll
        for (int m = 1; m <= 4; m <<= 1)
            #pragma unroll
            for (int rr = 0; rr < 4; rr++) sm[rr] += __shfl_xor(sm[rr], m);
        #pragma unroll
        for (int rr = 0; rr < 4; rr++) sim[mt][rr] = e[rr] / sm[rr];
    }

    // ---- weighted GEMM over t (W streamed from L1/L2, dist-1 n-prefetch) ----
    const bf16x8* wb = reinterpret_cast<const bf16x8*>(wsw);
    int nt0 = cb * 4;
    bf16x8 buf[2][4];
    #pragma unroll
    for (int k = 0; k < 4; k++)
        buf[0][k] = wb[(size_t)((0 * 8 + nt0) * 4 + k) * 64 + lane];

    f32x4 o[2][4] = {};

    #pragma unroll 1
    for (int t = 0; t < Tq; t++) {
        // per-row sim weight for this t: held by lane (quad, l16=t), already f32x4 over rows
        f32x4 s0, s1;
        int src = (lane & 48) | t;
        #pragma unroll
        for (int rr = 0; rr < 4; rr++) {
            s0[rr] = __shfl(sim[0][rr], src);
            s1[rr] = __shfl(sim[1][rr], src);
        }
        #pragma unroll
        for (int n = 0; n < 4; n++) {
            int cur = n & 1;
            {   // prefetch (t, n+1); wraps t=7,n=3 -> t=0 (unused)
                int n2 = (n + 1) & 3;
                int t2 = (n == 3) ? ((t + 1) & 7) : t;
                #pragma unroll
                for (int k = 0; k < 4; k++)
                    buf[cur ^ 1][k] = wb[(size_t)((t2 * 8 + nt0 + n2) * 4 + k) * 64 + lane];
            }
            float bias = bxl[t][n * 16 + l16];
            f32x4 y0 = {bias, bias, bias, bias};
            f32x4 y1 = {bias, bias, bias, bias};
            #pragma unroll
            for (int k = 0; k < 4; k++) {
                y0 = __builtin_amdgcn_mfma_f32_16x16x32_bf16(a[0][k], buf[cur][k], y0, 0, 0, 0);
                y1 = __builtin_amdgcn_mfma_f32_16x16x32_bf16(a[1][k], buf[cur][k], y1, 0, 0, 0);
            }
            #pragma unroll
            for (int rr = 0; rr < 4; rr++) {
                o[0][n][rr] += s0[rr] * y0[rr];
                o[1][n][rr] += s1[rr] * y1[rr];
            }
        }
    }

    // ---- epilogue: pure NT stores. C/D: col=lane&15, row=quad*4+reg ----
    #pragma unroll
    for (int mt = 0; mt < 2; mt++)
        #pragma unroll
        for (int rr = 0; rr < 4; rr++) {
            size_t row = wrow + mt * 16 + quad * 4 + rr;
            #pragma unroll
            for (int n = 0; n < 4; n++)
                __builtin_nontemporal_store(o[mt][n][rr], out + row * 128 + cb * 64 + n * 16 + l16);
        }
}

extern "C" void kernel_launch(void* const* d_in, const int* in_sizes, int n_in,
                              void* d_out, int out_size, void* d_ws, size_t ws_size,
                              hipStream_t stream) {
    const float* x   = (const float*)d_in[0];   // [B,S,D] fp32
    const float* Wx  = (const float*)d_in[1];   // [T,D,D] fp32
    const float* bx  = (const float*)d_in[2];   // [T,D]   fp32
    const float* p   = (const float*)d_in[3];   // [T,1,D] fp32
    float* out = (float*)d_out;

    unsigned short* ws = (unsigned short*)d_ws;  // 131072 W' shorts + 4096 P shorts

    prep_kernel<<<dim3(513), dim3(256), 0, stream>>>(Wx, p, ws);
    main_kernel<<<dim3(Mq / 128 * 2), dim3(256), 0, stream>>>(x, ws, bx, p, out);
}

// Round 7
// 122.835 us; speedup vs baseline: 1.1384x; 1.0148x over previous
//
#include <hip/hip_runtime.h>

// Problem constants
#define Tq 8
#define Mq 65536   // B*S rows

typedef short bf16x8 __attribute__((ext_vector_type(8)));
typedef float f32x4 __attribute__((ext_vector_type(4)));

static __device__ __forceinline__ unsigned short f2bf(float f) {
    unsigned int u = __float_as_uint(f);
    unsigned int r = (u + 0x7FFFu + ((u >> 16) & 1u)) >> 16;
    return (unsigned short)r;
}

// ---------------------------------------------------------------------------
// prep: blocks 0..511: W' = (W + I) fp32->bf16 in MFMA B-fragment order
//       (identity fold: softmax weights sum to 1 -> residual in diagonal).
//       block 512: P fragments (p in B-layout, cols 8..15 zero) for MFMA dots.
// Fragment flat index: (((t*8+nt)*4+k)*64+lane)*8+j -> per-t contiguous 32 KB,
// lane-contiguous 16B chunks (coalesced global_load_lds staging in main).
// ---------------------------------------------------------------------------
__global__ void prep_kernel(const float* __restrict__ W, const float* __restrict__ p,
                            unsigned short* __restrict__ ws) {
    int b = blockIdx.x;
    if (b < 512) {
        int i = b * 256 + threadIdx.x;   // T*D*D = 131072
        int j    = i & 7;
        int lane = (i >> 3) & 63;
        int k    = (i >> 9) & 3;
        int n    = (i >> 11) & 7;
        int t    = i >> 14;
        int e = n * 16 + (lane & 15);
        int d = k * 32 + (lane >> 4) * 8 + j;
        float w = W[(t * 128 + e) * 128 + d];
        if (e == d) w += 1.0f;
        ws[i] = f2bf(w);
    } else {
        // P fragments: 4096 shorts at offset 131072. index (k*64+lane)*8+j
        #pragma unroll
        for (int u = 0; u < 16; u++) {
            int i = u * 256 + threadIdx.x;
            int j    = i & 7;
            int lane = (i >> 3) & 63;
            int k    = i >> 9;
            int l16  = lane & 15;
            int quad = lane >> 4;
            int d = k * 32 + quad * 8 + j;
            float v = (l16 < Tq) ? p[l16 * 128 + d] : 0.0f;
            ws[131072 + i] = f2bf(v);
        }
    }
}

// ---------------------------------------------------------------------------
// main: block = 128 rows x 128 cols (256 thr, 4 waves), wave = 64r x 64c
// (4mt x 4nt -> 64 MFMA per 16 KB W slice; W bytes/MFMA 4x better than R6).
// Phase A: coalesced x -> bf16 LDS (+|x|^2 via LDS atomicAdd), A-frags to
//   registers, MFMA p-dots, cross-lane softmax (sim stays in C-layout regs).
// Phase B: the x-LDS region is REUSED as a 2x32KB W double buffer filled with
//   global_load_lds(16B); compute(t) overlaps staging(t+1) - the barrier that
//   drains the prefetch is a whole t-iteration later (true async pipeline).
// LDS ~70 KB -> 2 blocks/CU; W crosses L2 once per block, not once per wave.
// ---------------------------------------------------------------------------
__global__ __launch_bounds__(256, 2) void main_kernel(const float* __restrict__ x,
                                                      const unsigned short* __restrict__ wsw,
                                                      const float* __restrict__ bx,
                                                      const float* __restrict__ p,
                                                      float* __restrict__ out) {
    __shared__ unsigned short un[32768];   // 64 KB union: phase A xs[128][136] / phase B W dbuf
    __shared__ float bxl[Tq][128];
    __shared__ float ssql[128];
    __shared__ float pinv[Tq];

    int tid  = threadIdx.x;
    int wid  = tid >> 6;
    int lane = tid & 63;
    int l16  = lane & 15;
    int quad = lane >> 4;
    size_t m0 = (size_t)blockIdx.x * 128;
    int mrow = (wid >> 1) * 64;      // wave row base (0/64)
    int nt0  = (wid & 1) * 4;        // wave col-tile base (nt 0..3 / 4..7)
    int ncol = (wid & 1) * 64;

    // ---- init LDS + stage bias + pinv ----
    if (tid < 128) ssql[tid] = 0.f;
    reinterpret_cast<f32x4*>(&bxl[0][0])[tid] = reinterpret_cast<const f32x4*>(bx)[tid];
    if (tid < Tq) {
        const f32x4* pg = reinterpret_cast<const f32x4*>(p) + tid * 32;
        float s = 0.f;
        #pragma unroll
        for (int i = 0; i < 32; i++) {
            f32x4 v = pg[i];
            s += v.x * v.x + v.y * v.y + v.z * v.z + v.w * v.w;
        }
        pinv[tid] = rsqrtf(s);
    }
    __syncthreads();

    // ---- stage x tile -> bf16 LDS (coalesced) + per-row |x|^2 atomics ----
    const f32x4* xg4 = reinterpret_cast<const f32x4*>(x + m0 * 128);
    #pragma unroll
    for (int it = 0; it < 16; it++) {
        int flat = it * 256 + tid;        // 4096 float4
        int row = flat >> 5;
        int c4  = flat & 31;
        f32x4 v = __builtin_nontemporal_load(xg4 + flat);
        atomicAdd(&ssql[row], v.x * v.x + v.y * v.y + v.z * v.z + v.w * v.w);
        ushort4 bv;
        bv.x = f2bf(v.x); bv.y = f2bf(v.y); bv.z = f2bf(v.z); bv.w = f2bf(v.w);
        *reinterpret_cast<ushort4*>(&un[row * 136 + c4 * 4]) = bv;
    }
    __syncthreads();   // xs + ssql complete

    // ---- A fragments to registers (reused across all 8 t + p-dots) ----
    bf16x8 a[4][4];
    #pragma unroll
    for (int mt = 0; mt < 4; mt++)
        #pragma unroll
        for (int k = 0; k < 4; k++)
            a[mt][k] = *reinterpret_cast<const bf16x8*>(&un[(mrow + mt * 16 + l16) * 136 + k * 32 + quad * 8]);

    // per-output-row 1/|x| (C-layout rows: quad*4+rr)
    f32x4 xinvv[4];
    #pragma unroll
    for (int mt = 0; mt < 4; mt++)
        #pragma unroll
        for (int rr = 0; rr < 4; rr++)
            xinvv[mt][rr] = rsqrtf(ssql[mrow + mt * 16 + quad * 4 + rr]);

    // p-dots via MFMA (cols = t for l16<8)
    const bf16x8* pf = reinterpret_cast<const bf16x8*>(wsw) + 16384;
    bf16x8 pfrag[4];
    #pragma unroll
    for (int k = 0; k < 4; k++) pfrag[k] = pf[k * 64 + lane];
    f32x4 d[4] = {};
    #pragma unroll
    for (int k = 0; k < 4; k++)
        #pragma unroll
        for (int mt = 0; mt < 4; mt++)
            d[mt] = __builtin_amdgcn_mfma_f32_16x16x32_bf16(a[mt][k], pfrag[k], d[mt], 0, 0, 0);

    __syncthreads();   // all waves done reading xs -> un becomes W dbuf

    // ---- stage W[t=0] into buf0 (async, 16B direct-to-LDS) ----
    const char* wsrc = reinterpret_cast<const char*>(wsw);
    char* lbase = reinterpret_cast<char*>(un);
    {
        #pragma unroll
        for (int it = 0; it < 8; it++) {
            int off = it * 4096 + wid * 1024;
            __builtin_amdgcn_global_load_lds(
                (const __attribute__((address_space(1))) unsigned int*)(wsrc + off + lane * 16),
                (__attribute__((address_space(3))) unsigned int*)(lbase + off),
                16, 0, 0);
        }
    }

    // ---- cosine + softmax (registers only; overlaps W[0] staging) ----
    float pv = pinv[l16 & 7];
    f32x4 sim[4];
    #pragma unroll
    for (int mt = 0; mt < 4; mt++) {
        f32x4 c;
        #pragma unroll
        for (int rr = 0; rr < 4; rr++) c[rr] = d[mt][rr] * xinvv[mt][rr] * pv;
        f32x4 mx = c;
        #pragma unroll
        for (int m = 1; m <= 4; m <<= 1)
            #pragma unroll
            for (int rr = 0; rr < 4; rr++) mx[rr] = fmaxf(mx[rr], __shfl_xor(mx[rr], m));
        #pragma unroll
        for (int rr = 0; rr < 4; rr++) c[rr] = __expf(c[rr] - mx[rr]);
        f32x4 sm = c;
        #pragma unroll
        for (int m = 1; m <= 4; m <<= 1)
            #pragma unroll
            for (int rr = 0; rr < 4; rr++) sm[rr] += __shfl_xor(sm[rr], m);
        #pragma unroll
        for (int rr = 0; rr < 4; rr++) sim[mt][rr] = c[rr] / sm[rr];
    }

    // ---- t-loop: compute(t) from buf[t&1], stage(t+1) into buf[~t&1] ----
    f32x4 o[4][4] = {};
    #pragma unroll 1
    for (int t = 0; t < Tq; t++) {
        __syncthreads();   // drains vmcnt: buf[t&1] fully staged; waves aligned
        if (t < 7) {
            const char* ws2 = wsrc + (t + 1) * 32768;
            char* ld2 = lbase + ((t + 1) & 1) * 32768;
            #pragma unroll
            for (int it = 0; it < 8; it++) {
                int off = it * 4096 + wid * 1024;
                __builtin_amdgcn_global_load_lds(
                    (const __attribute__((address_space(1))) unsigned int*)(ws2 + off + lane * 16),
                    (__attribute__((address_space(3))) unsigned int*)(ld2 + off),
                    16, 0, 0);
            }
        }
        // per-row sim weight for this t (held by lane l16=t, same quad)
        f32x4 s[4];
        int src = (lane & 48) | t;
        #pragma unroll
        for (int mt = 0; mt < 4; mt++)
            #pragma unroll
            for (int rr = 0; rr < 4; rr++)
                s[mt][rr] = __shfl(sim[mt][rr], src);

        const unsigned short* wl = un + (t & 1) * 16384;   // ushort index
        bf16x8 bfr[2][4];
        #pragma unroll
        for (int k = 0; k < 4; k++)
            bfr[0][k] = *reinterpret_cast<const bf16x8*>(&wl[(((nt0) * 4 + k) * 64 + lane) * 8]);

        #pragma unroll
        for (int n = 0; n < 4; n++) {
            int cur = n & 1;
            if (n < 3) {
                #pragma unroll
                for (int k = 0; k < 4; k++)
                    bfr[cur ^ 1][k] = *reinterpret_cast<const bf16x8*>(&wl[(((nt0 + n + 1) * 4 + k) * 64 + lane) * 8]);
            }
            float bias = bxl[t][ncol + n * 16 + l16];
            f32x4 y[4];
            #pragma unroll
            for (int mt = 0; mt < 4; mt++) y[mt] = (f32x4){bias, bias, bias, bias};
            #pragma unroll
            for (int k = 0; k < 4; k++)
                #pragma unroll
                for (int mt = 0; mt < 4; mt++)
                    y[mt] = __builtin_amdgcn_mfma_f32_16x16x32_bf16(a[mt][k], bfr[cur][k], y[mt], 0, 0, 0);
            #pragma unroll
            for (int mt = 0; mt < 4; mt++)
                #pragma unroll
                for (int rr = 0; rr < 4; rr++)
                    o[mt][n][rr] += s[mt][rr] * y[mt][rr];
        }
    }

    // ---- epilogue: pure NT stores. C/D: col=lane&15, row=quad*4+reg ----
    #pragma unroll
    for (int mt = 0; mt < 4; mt++)
        #pragma unroll
        for (int rr = 0; rr < 4; rr++) {
            size_t row = m0 + mrow + mt * 16 + quad * 4 + rr;
            #pragma unroll
            for (int n = 0; n < 4; n++)
                __builtin_nontemporal_store(o[mt][n][rr], out + row * 128 + ncol + n * 16 + l16);
        }
}

extern "C" void kernel_launch(void* const* d_in, const int* in_sizes, int n_in,
                              void* d_out, int out_size, void* d_ws, size_t ws_size,
                              hipStream_t stream) {
    const float* x   = (const float*)d_in[0];   // [B,S,D] fp32
    const float* Wx  = (const float*)d_in[1];   // [T,D,D] fp32
    const float* bx  = (const float*)d_in[2];   // [T,D]   fp32
    const float* p   = (const float*)d_in[3];   // [T,1,D] fp32
    float* out = (float*)d_out;

    unsigned short* ws = (unsigned short*)d_ws;  // 131072 W' shorts + 4096 P shorts

    prep_kernel<<<dim3(513), dim3(256), 0, stream>>>(Wx, p, ws);
    main_kernel<<<dim3(Mq / 128), dim3(256), 0, stream>>>(x, ws, bx, p, out);
}